// Round 4
// baseline (103.064 us; speedup 1.0000x reference)
//
#include <hip/hip_runtime.h>
#include <hip/hip_bf16.h>

#define NB 8
#define NC 128
#define NH 48
#define NW 64
#define NS 3072  // NH*NW
#define EPSF 1e-6f

#define GLOBAL_AS __attribute__((address_space(1)))
#define LDS_AS __attribute__((address_space(3)))

typedef __bf16 bf16x8 __attribute__((ext_vector_type(8)));
typedef float f32x4 __attribute__((ext_vector_type(4)));

// ---------------------------------------------------------------------------
// Fused transpose+convert for BOTH inputs: f32 [B][C][S] -> bf16 [B][S][C].
// 1D grid, b = id&7 pins batch to XCD.
// Tile: 32 f-rows x 64 channels, f32 LDS [32][65] (conflict-free both phases).
// ---------------------------------------------------------------------------
__global__ __launch_bounds__(256) void transpose_both(
    const float* __restrict__ x, const float* __restrict__ y,
    __hip_bfloat16* __restrict__ AT, __hip_bfloat16* __restrict__ BT) {
  __shared__ float tile[32][65];
  const int id = blockIdx.x;
  const int b = id & 7;
  const int which = (id >> 3) & 1;
  const int rr = id >> 4;  // 0..191
  const int f0 = (rr % 96) * 32, c0 = (rr / 96) * 64;
  const float* src = which ? y : x;
  __hip_bfloat16* dst = which ? BT : AT;
  const int t = threadIdx.x;

  const int fi = t & 31, ci0 = t >> 5;
  const float* sp = src + ((size_t)b * NC + c0) * NS + f0;
#pragma unroll
  for (int i = 0; i < 8; ++i) {
    int ci = ci0 + i * 8;
    tile[fi][ci] = sp[(size_t)ci * NS + fi];
  }
  __syncthreads();

  const int co = t & 63, fo0 = t >> 6;
#pragma unroll
  for (int i = 0; i < 8; ++i) {
    int fo = fo0 + i * 4;
    int f = f0 + fo;
    int k = which ? f : ((f & 63) * NH + (f >> 6));  // x: k = v*H + u
    dst[((size_t)b * NS + k) * NC + c0 + co] = __float2bfloat16(tile[fo][co]);
  }
}

// ---------------------------------------------------------------------------
// GEMM tile 128(m) x 64(n), K=C=128, 4 waves as 2x2 of 64x32, acc[4][2].
// LDS: A 32 KB + B 16 KB (+256 B rn) = 48.4 KB -> 3 blocks/CU for deeper
// store/stage overlap. Staging via global_load_lds w=16, linear LDS dest,
// inverse-swizzled global source; reads use g ^ (row&7) (layout identical to
// the verified round-1 kernel).
// WRITE=false: part_out[mt][b][n] = sum_m relu(T)^2
// WRITE=true : out[b][m][n] = relu(T)*rsqrt(sum_mt part_in + eps); epilogue
//   repacks through f32 LDS [128][65] then streams dwordx4 full-line stores.
// ---------------------------------------------------------------------------
template <bool WRITE>
__global__ __launch_bounds__(256, 3) void corr_gemm(
    const __hip_bfloat16* __restrict__ AT,
    const __hip_bfloat16* __restrict__ BT,
    const float* __restrict__ part_in, float* __restrict__ part_out,
    float* __restrict__ out) {
  __shared__ char smem[49664];  // 0..32K: A, 32K..48K: B, 48K..+256: rn
  float* rnc = (float*)(smem + 49152);
  const int id = blockIdx.x;
  const int b = id & 7;
  const int tl = id >> 3;          // 0..1151
  const int mt = tl / 48, nt = tl - mt * 48;
  const int t = threadIdx.x;
  const int lane = t & 63, wid = t >> 6;
  const int wm = wid >> 1, wn = wid & 1;
  const int l15 = lane & 15, kg = lane >> 4;

  // ---- async stage: A = 32 chunks of 1 KB, B = 16 chunks ----
  const char* Ag = (const char*)(AT + ((size_t)b * NS + mt * 128) * NC);
  const char* Bg = (const char*)(BT + ((size_t)b * NS + nt * 64) * NC);
  {
    const int lr = lane >> 4, lg = lane & 15;
#pragma unroll
    for (int i = 0; i < 8; ++i) {
      int c = wid * 8 + i;        // A chunk 0..31
      int row = c * 4 + lr;
      int g = lg ^ (row & 7);
      __builtin_amdgcn_global_load_lds(
          (const GLOBAL_AS unsigned*)(Ag + row * 256 + g * 16),
          (LDS_AS unsigned*)(smem + c * 1024), 16, 0, 0);
    }
#pragma unroll
    for (int i = 0; i < 4; ++i) {
      int c = wid * 4 + i;        // B chunk 0..15
      int row = c * 4 + lr;
      int g = lg ^ (row & 7);
      __builtin_amdgcn_global_load_lds(
          (const GLOBAL_AS unsigned*)(Bg + row * 256 + g * 16),
          (LDS_AS unsigned*)(smem + 32768 + c * 1024), 16, 0, 0);
    }
  }
  if (WRITE) {
    // fused norm for this block's 64 columns (overlaps staging)
    if (t < 64) {
      float s = 0.f;
#pragma unroll
      for (int q = 0; q < 24; ++q)
        s += part_in[(size_t)q * (NB * NS) + (size_t)b * NS + nt * 64 + t];
      rnc[t] = rsqrtf(s + EPSF);
    }
  }
  __syncthreads();  // drains vmcnt (global_load_lds) + lgkm (rnc)

  // ---- MFMA main: 4 K-steps of 32, 8 MFMA each ----
  f32x4 acc[4][2] = {};
  const int rx = l15 & 7;
#pragma unroll
  for (int kk = 0; kk < 4; ++kk) {
    int g = (kk * 4 + kg) ^ rx;
    bf16x8 a[4], bb[2];
#pragma unroll
    for (int mi = 0; mi < 4; ++mi) {
      int row = wm * 64 + mi * 16 + l15;
      a[mi] = *(const bf16x8*)(smem + row * 256 + g * 16);
    }
#pragma unroll
    for (int ni = 0; ni < 2; ++ni) {
      int row = wn * 32 + ni * 16 + l15;
      bb[ni] = *(const bf16x8*)(smem + 32768 + row * 256 + g * 16);
    }
#pragma unroll
    for (int mi = 0; mi < 4; ++mi)
#pragma unroll
      for (int ni = 0; ni < 2; ++ni)
        acc[mi][ni] = __builtin_amdgcn_mfma_f32_16x16x32_bf16(
            a[mi], bb[ni], acc[mi][ni], 0, 0, 0);
  }

  if (!WRITE) {
    // per-column (n) sum of relu^2 over this tile's 128 rows
    float cs[2] = {0.f, 0.f};
#pragma unroll
    for (int ni = 0; ni < 2; ++ni)
#pragma unroll
      for (int mi = 0; mi < 4; ++mi)
#pragma unroll
        for (int r = 0; r < 4; ++r) {
          float v = fmaxf(acc[mi][ni][r], 0.f);
          cs[ni] += v * v;
        }
#pragma unroll
    for (int ni = 0; ni < 2; ++ni) {
      cs[ni] += __shfl_xor(cs[ni], 16, 64);
      cs[ni] += __shfl_xor(cs[ni], 32, 64);
    }
    __syncthreads();  // tiles consumed; reuse LDS
    float* csum = (float*)smem;  // [2 wm][64]
    if (kg == 0) {
#pragma unroll
      for (int ni = 0; ni < 2; ++ni)
        csum[wm * 64 + wn * 32 + ni * 16 + l15] = cs[ni];
    }
    __syncthreads();
    if (t < 64) {
      float s = csum[t] + csum[64 + t];
      part_out[(size_t)mt * (NB * NS) + (size_t)b * NS + nt * 64 + t] = s;
    }
  } else {
    float rnv[2];
#pragma unroll
    for (int ni = 0; ni < 2; ++ni) rnv[ni] = rnc[wn * 32 + ni * 16 + l15];
    __syncthreads();  // tiles + rnc fully consumed

    // repack scaled tile into f32 [128][65] (pad keeps rows bank-staggered)
    float* tf = (float*)smem;
#pragma unroll
    for (int mi = 0; mi < 4; ++mi)
#pragma unroll
      for (int ni = 0; ni < 2; ++ni)
#pragma unroll
        for (int r = 0; r < 4; ++r) {
          int row = wm * 64 + mi * 16 + kg * 4 + r;
          int col = wn * 32 + ni * 16 + l15;
          tf[row * 65 + col] = fmaxf(acc[mi][ni][r], 0.f) * rnv[ni];
        }
    __syncthreads();

    // stream out: 16 rows x 256 B per block-instr step (all-full 128 B lines)
    float* ob = out + (size_t)b * NS * NS + (size_t)(mt * 128) * NS + nt * 64;
    const int rsub = t >> 4, c4 = (t & 15) * 4;
#pragma unroll
    for (int it = 0; it < 8; ++it) {
      int row = it * 16 + rsub;
      f32x4 v = *(const f32x4*)&tf[row * 65 + c4];
      __builtin_nontemporal_store(v, (f32x4*)&ob[(size_t)row * NS + c4]);
    }
  }
}

extern "C" void kernel_launch(void* const* d_in, const int* in_sizes, int n_in,
                              void* d_out, int out_size, void* d_ws,
                              size_t ws_size, hipStream_t stream) {
  const float* x = (const float*)d_in[0];
  const float* y = (const float*)d_in[1];
  float* out = (float*)d_out;
  char* ws = (char*)d_ws;

  const size_t AT_OFF = 0;           // 8*3072*128*2 = 6,291,456
  const size_t BT_OFF = 6291456;     // + 6,291,456
  const size_t PART_OFF = 12582912;  // 24*24576*4 = 2,359,296
  const size_t NEED = 14942208;
  if (ws_size < NEED) return;

  __hip_bfloat16* AT = (__hip_bfloat16*)(ws + AT_OFF);
  __hip_bfloat16* BT = (__hip_bfloat16*)(ws + BT_OFF);
  float* part = (float*)(ws + PART_OFF);

  dim3 tb(256);
  transpose_both<<<dim3(3072), tb, 0, stream>>>(x, y, AT, BT);
  corr_gemm<false><<<dim3(9216), tb, 0, stream>>>(AT, BT, nullptr, part,
                                                  nullptr);
  corr_gemm<true><<<dim3(9216), tb, 0, stream>>>(AT, BT, part, nullptr, out);
}

// Round 5
// 102.351 us; speedup vs baseline: 1.0070x; 1.0070x over previous
//
#include <hip/hip_runtime.h>
#include <hip/hip_bf16.h>

#define NB 8
#define NC 128
#define NH 48
#define NW 64
#define NS 3072  // NH*NW
#define EPSF 1e-6f

#define GLOBAL_AS __attribute__((address_space(1)))
#define LDS_AS __attribute__((address_space(3)))

typedef __bf16 bf16x8 __attribute__((ext_vector_type(8)));
typedef float f32x4 __attribute__((ext_vector_type(4)));

// ---------------------------------------------------------------------------
// Fused transpose+convert for BOTH inputs: f32 [B][C][S] -> bf16 [B][S][C].
// 1D grid, b = id&7 pins batch to XCD.
// ---------------------------------------------------------------------------
__global__ __launch_bounds__(256) void transpose_both(
    const float* __restrict__ x, const float* __restrict__ y,
    __hip_bfloat16* __restrict__ AT, __hip_bfloat16* __restrict__ BT) {
  __shared__ float tile[32][65];
  const int id = blockIdx.x;
  const int b = id & 7;
  const int which = (id >> 3) & 1;
  const int rr = id >> 4;  // 0..191
  const int f0 = (rr % 96) * 32, c0 = (rr / 96) * 64;
  const float* src = which ? y : x;
  __hip_bfloat16* dst = which ? BT : AT;
  const int t = threadIdx.x;

  const int fi = t & 31, ci0 = t >> 5;
  const float* sp = src + ((size_t)b * NC + c0) * NS + f0;
#pragma unroll
  for (int i = 0; i < 8; ++i) {
    int ci = ci0 + i * 8;
    tile[fi][ci] = sp[(size_t)ci * NS + fi];
  }
  __syncthreads();

  const int co = t & 63, fo0 = t >> 6;
#pragma unroll
  for (int i = 0; i < 8; ++i) {
    int fo = fo0 + i * 4;
    int f = f0 + fo;
    int k = which ? f : ((f & 63) * NH + (f >> 6));  // x: k = v*H + u
    dst[((size_t)b * NS + k) * NC + c0 + co] = __float2bfloat16(tile[fo][co]);
  }
}

// ---------------------------------------------------------------------------
// Pass 1 (column-persistent): one block per (b, nt); B-tile resident, A-tiles
// double-buffered over mt=0..23; per-column sum of relu(T)^2 accumulates in
// registers; writes rn = rsqrt(sum+eps) directly.  LDS 96 KB -> 1 block/CU.
// Swizzle identical to verified kernels: linear LDS dest, inverse-swizzled
// global source, read granule g ^ (row&7).
// ---------------------------------------------------------------------------
__device__ __forceinline__ void stage_tile(const char* gsrc, char* ldst,
                                           int wid, int lane) {
  const int lr = lane >> 4, lg = lane & 15;
#pragma unroll
  for (int i = 0; i < 8; ++i) {
    int c = wid * 8 + i;   // 1 KB chunk 0..31
    int row = c * 4 + lr;
    int g = lg ^ (row & 7);
    __builtin_amdgcn_global_load_lds(
        (const GLOBAL_AS unsigned*)(gsrc + row * 256 + g * 16),
        (LDS_AS unsigned*)(ldst + c * 1024), 16, 0, 0);
  }
}

__device__ __forceinline__ void gemm_step(const char* As, const char* Bs,
                                          float cs[4], int wm, int wn,
                                          int l15, int kg) {
  f32x4 acc[4][4] = {};
  const int rx = l15 & 7;
#pragma unroll
  for (int kk = 0; kk < 4; ++kk) {
    int g = (kk * 4 + kg) ^ rx;
    bf16x8 a[4], bb[4];
#pragma unroll
    for (int mi = 0; mi < 4; ++mi)
      a[mi] = *(const bf16x8*)(As + (wm * 64 + mi * 16 + l15) * 256 + g * 16);
#pragma unroll
    for (int ni = 0; ni < 4; ++ni)
      bb[ni] = *(const bf16x8*)(Bs + (wn * 64 + ni * 16 + l15) * 256 + g * 16);
#pragma unroll
    for (int mi = 0; mi < 4; ++mi)
#pragma unroll
      for (int ni = 0; ni < 4; ++ni)
        acc[mi][ni] = __builtin_amdgcn_mfma_f32_16x16x32_bf16(
            a[mi], bb[ni], acc[mi][ni], 0, 0, 0);
  }
#pragma unroll
  for (int ni = 0; ni < 4; ++ni)
#pragma unroll
    for (int mi = 0; mi < 4; ++mi)
#pragma unroll
      for (int r = 0; r < 4; ++r) {
        float v = fmaxf(acc[mi][ni][r], 0.f);
        cs[ni] += v * v;
      }
}

__global__ __launch_bounds__(256, 1) void corr_norm(
    const __hip_bfloat16* __restrict__ AT,
    const __hip_bfloat16* __restrict__ BT, float* __restrict__ rn) {
  __shared__ char smem[98304];  // A0 32K | A1 32K | B 32K
  char* Bs = smem + 65536;
  const int id = blockIdx.x;  // 192
  const int b = id & 7;       // XCD pin
  const int nt = id >> 3;     // 0..23
  const int t = threadIdx.x;
  const int lane = t & 63, wid = t >> 6;
  const int wm = wid >> 1, wn = wid & 1;
  const int l15 = lane & 15, kg = lane >> 4;

  const char* Ab = (const char*)(AT + (size_t)b * NS * NC);
  const char* Bg = (const char*)(BT + ((size_t)b * NS + nt * 128) * NC);

  stage_tile(Bg, Bs, wid, lane);
  stage_tile(Ab, smem, wid, lane);  // mt = 0 -> buf0
  __syncthreads();

  float cs[4] = {0.f, 0.f, 0.f, 0.f};
#pragma unroll 1
  for (int mt = 0; mt < 24; mt += 2) {
    // compute buf0 (tile mt), prefetch mt+1 -> buf1
    stage_tile(Ab + (size_t)(mt + 1) * 32768, smem + 32768, wid, lane);
    gemm_step(smem, Bs, cs, wm, wn, l15, kg);
    __syncthreads();
    // compute buf1 (tile mt+1), prefetch mt+2 -> buf0
    if (mt + 2 < 24)
      stage_tile(Ab + (size_t)(mt + 2) * 32768, smem, wid, lane);
    gemm_step(smem + 32768, Bs, cs, wm, wn, l15, kg);
    __syncthreads();
  }

#pragma unroll
  for (int ni = 0; ni < 4; ++ni) {
    cs[ni] += __shfl_xor(cs[ni], 16, 64);
    cs[ni] += __shfl_xor(cs[ni], 32, 64);
  }
  float* csum = (float*)smem;  // [2][128]
  if (kg == 0) {
#pragma unroll
    for (int ni = 0; ni < 4; ++ni)
      csum[wm * 128 + wn * 64 + ni * 16 + l15] = cs[ni];
  }
  __syncthreads();
  if (t < 128) {
    float s = csum[t] + csum[128 + t];
    rn[(size_t)b * NS + nt * 128 + t] = rsqrtf(s + EPSF);
  }
}

// ---------------------------------------------------------------------------
// Pass 2: round-3 verified kernel; rn loaded from global (no reduce).
// Epilogue repacks the 128x128 f32 tile through LDS [128][129] then streams
// dwordx4 full-line nt stores (2 rows x 512 B per wave instruction).
// ---------------------------------------------------------------------------
__global__ __launch_bounds__(256, 2) void corr_out(
    const __hip_bfloat16* __restrict__ AT,
    const __hip_bfloat16* __restrict__ BT, const float* __restrict__ rn,
    float* __restrict__ out) {
  __shared__ char smem[66560];  // A 32K | B 32K | rn 512 B
  float* rnc = (float*)(smem + 65536);
  const int id = blockIdx.x;
  const int b = id & 7;
  const int tl = id >> 3;
  const int mt = tl / 24, nt = tl - mt * 24;
  const int t = threadIdx.x;
  const int lane = t & 63, wid = t >> 6;
  const int wm = wid >> 1, wn = wid & 1;
  const int l15 = lane & 15, kg = lane >> 4;

  const char* Ag = (const char*)(AT + ((size_t)b * NS + mt * 128) * NC);
  const char* Bg = (const char*)(BT + ((size_t)b * NS + nt * 128) * NC);
  stage_tile(Ag, smem, wid, lane);
  stage_tile(Bg, smem + 32768, wid, lane);
  if (t < 128) rnc[t] = rn[(size_t)b * NS + nt * 128 + t];
  __syncthreads();

  f32x4 acc[4][4] = {};
  const int rx = l15 & 7;
#pragma unroll
  for (int kk = 0; kk < 4; ++kk) {
    int g = (kk * 4 + kg) ^ rx;
    bf16x8 a[4], bb[4];
#pragma unroll
    for (int mi = 0; mi < 4; ++mi)
      a[mi] = *(const bf16x8*)(smem + (wm * 64 + mi * 16 + l15) * 256 + g * 16);
#pragma unroll
    for (int ni = 0; ni < 4; ++ni)
      bb[ni] = *(const bf16x8*)(smem + 32768 +
                                (wn * 64 + ni * 16 + l15) * 256 + g * 16);
#pragma unroll
    for (int mi = 0; mi < 4; ++mi)
#pragma unroll
      for (int ni = 0; ni < 4; ++ni)
        acc[mi][ni] = __builtin_amdgcn_mfma_f32_16x16x32_bf16(
            a[mi], bb[ni], acc[mi][ni], 0, 0, 0);
  }

  float rnv[4];
#pragma unroll
  for (int ni = 0; ni < 4; ++ni) rnv[ni] = rnc[wn * 64 + ni * 16 + l15];
  __syncthreads();  // tiles + rnc fully consumed

  float* tf = (float*)smem;  // [128][129]
#pragma unroll
  for (int mi = 0; mi < 4; ++mi)
#pragma unroll
    for (int ni = 0; ni < 4; ++ni)
#pragma unroll
      for (int r = 0; r < 4; ++r) {
        int row = wm * 64 + mi * 16 + kg * 4 + r;
        int col = wn * 64 + ni * 16 + l15;
        tf[row * 129 + col] = fmaxf(acc[mi][ni][r], 0.f) * rnv[ni];
      }
  __syncthreads();

  float* ob = out + (size_t)b * NS * NS + (size_t)(mt * 128) * NS + nt * 128;
  const int rsub = t >> 5, c4 = (t & 31) * 4;
#pragma unroll
  for (int it = 0; it < 16; ++it) {
    int row = it * 8 + rsub;
    f32x4 v = *(const f32x4*)&tf[row * 129 + c4];
    __builtin_nontemporal_store(v, (f32x4*)&ob[(size_t)row * NS + c4]);
  }
}

extern "C" void kernel_launch(void* const* d_in, const int* in_sizes, int n_in,
                              void* d_out, int out_size, void* d_ws,
                              size_t ws_size, hipStream_t stream) {
  const float* x = (const float*)d_in[0];
  const float* y = (const float*)d_in[1];
  float* out = (float*)d_out;
  char* ws = (char*)d_ws;

  const size_t AT_OFF = 0;         // 8*3072*128*2 = 6,291,456
  const size_t BT_OFF = 6291456;   // + 6,291,456
  const size_t RN_OFF = 12582912;  // 24576*4 = 98,304
  const size_t NEED = 12681216;
  if (ws_size < NEED) return;

  __hip_bfloat16* AT = (__hip_bfloat16*)(ws + AT_OFF);
  __hip_bfloat16* BT = (__hip_bfloat16*)(ws + BT_OFF);
  float* rn = (float*)(ws + RN_OFF);

  dim3 tb(256);
  transpose_both<<<dim3(3072), tb, 0, stream>>>(x, y, AT, BT);
  corr_norm<<<dim3(192), tb, 0, stream>>>(AT, BT, rn);
  corr_out<<<dim3(4608), tb, 0, stream>>>(AT, BT, rn, out);
}